// Round 2
// baseline (806.812 us; speedup 1.0000x reference)
//
#include <hip/hip_runtime.h>

#define NPTS 4096
#define NCH  64
#define NB   8
#define KNN  16

// ---------------- K1: xx[b,n] = sum_c x^2 in fp64 (effectively exact) ---------
__global__ __launch_bounds__(256) void k_xx(const float* __restrict__ x,
                                            double* __restrict__ xx) {
    int g = blockIdx.x * 256 + threadIdx.x;        // [0, 8*4096)
    int b = g >> 12, n = g & 4095;
    const float* xp = x + (size_t)b * NCH * NPTS + n;
    double acc = 0.0;
    #pragma unroll
    for (int c = 0; c < NCH; ++c) {
        double v = (double)xp[(size_t)c * NPTS];
        acc = fma(v, v, acc);
    }
    xx[g] = acc;
}

// ---------------- K2: KNN top-16 per query (fp64-exact distances) -------------
// Per block: 64 queries of batch b. Loop over 64 candidate tiles of 64.
// GEMM phase (fp64 accumulate) -> sD; scan phase: branch-free sorted-insert of
// f64-packed (dist, idx).
__global__ __launch_bounds__(256) void k_knn(const float* __restrict__ x,
                                             const double* __restrict__ xx,
                                             int* __restrict__ idx_out) {
    __shared__ __align__(16) float  sQ[4096];        // [c][q] 64x64
    __shared__ __align__(16) float  sM[4096];        // [c][m] 64x64
    __shared__ __align__(16) double sD[64 * 69];     // [q][m] pad->69 (2-way b64, free)
    __shared__ __align__(16) double sXm[64];

    const int tid = threadIdx.x;
    const int b   = blockIdx.y;
    const int q0  = blockIdx.x * 64;
    const float*  xb  = x  + (size_t)b * NCH * NPTS;
    const double* xxb = xx + (size_t)b * NPTS;

    for (int i = tid; i < 4096; i += 256) {
        int c = i >> 6, q = i & 63;
        sQ[i] = xb[(size_t)c * NPTS + q0 + q];
    }

    double s[16];
    #pragma unroll
    for (int i = 0; i < 16; ++i) s[i] = 0.0;

    const int ty = tid >> 4, tx = tid & 15;   // GEMM mapping: q=ty*4.., m=tx*4..
    const int sc = tid & 3,  qq = tid >> 2;   // scan mapping: 4 scanners per query
    const double xq = xxb[q0 + qq];           // xx of my query (fp64)

    for (int t = 0; t < 64; ++t) {
        const int m0 = t * 64;
        for (int i = tid; i < 4096; i += 256) {
            int c = i >> 6, m = i & 63;
            sM[i] = xb[(size_t)c * NPTS + m0 + m];
        }
        __syncthreads();   // SYNC_A: sM ready AND all prior-tile scans finished

        // sXm written here (after SYNC_A -> prior scan done; before SYNC_B ->
        // visible to this tile's scan). This placement fixes the round-1 race.
        if (tid < 64) sXm[tid] = xxb[m0 + tid];

        double acc[4][4];
        #pragma unroll
        for (int i = 0; i < 4; ++i)
            #pragma unroll
            for (int j = 0; j < 4; ++j) acc[i][j] = 0.0;

        const float4* q4 = (const float4*)sQ + ty;   // row stride 16 float4
        const float4* m4 = (const float4*)sM + tx;
        #pragma unroll 4
        for (int kk = 0; kk < 64; ++kk) {
            float4 a = q4[kk * 16];
            float4 v = m4[kk * 16];
            double ax = a.x, ay = a.y, az = a.z, aw = a.w;
            double vx = v.x, vy = v.y, vz = v.z, vw = v.w;
            acc[0][0] = fma(ax, vx, acc[0][0]);
            acc[0][1] = fma(ax, vy, acc[0][1]);
            acc[0][2] = fma(ax, vz, acc[0][2]);
            acc[0][3] = fma(ax, vw, acc[0][3]);
            acc[1][0] = fma(ay, vx, acc[1][0]);
            acc[1][1] = fma(ay, vy, acc[1][1]);
            acc[1][2] = fma(ay, vz, acc[1][2]);
            acc[1][3] = fma(ay, vw, acc[1][3]);
            acc[2][0] = fma(az, vx, acc[2][0]);
            acc[2][1] = fma(az, vy, acc[2][1]);
            acc[2][2] = fma(az, vz, acc[2][2]);
            acc[2][3] = fma(az, vw, acc[2][3]);
            acc[3][0] = fma(aw, vx, acc[3][0]);
            acc[3][1] = fma(aw, vy, acc[3][1]);
            acc[3][2] = fma(aw, vz, acc[3][2]);
            acc[3][3] = fma(aw, vw, acc[3][3]);
        }
        #pragma unroll
        for (int i = 0; i < 4; ++i) {
            double* dst = sD + (size_t)(ty * 4 + i) * 69 + tx * 4;
            dst[0] = acc[i][0]; dst[1] = acc[i][1];
            dst[2] = acc[i][2]; dst[3] = acc[i][3];
        }
        __syncthreads();   // SYNC_B: sD + sXm ready for scan

        const double* row = sD + (size_t)qq * 69;
        #pragma unroll
        for (int j = 0; j < 16; ++j) {
            int m = sc + 4 * j;
            double dot = row[m];
            double dv  = fma(2.0, dot, -(xq + sXm[m]));   // dist (exact-ish fp64)
            double pv  = dv + 4096.0;                     // positive, exp ~2^11
            unsigned long long bits =
                (((unsigned long long)__double_as_longlong(pv)) & 0xFFFFFFFFFFFFF000ULL)
                | (unsigned long long)(4095 - (m0 + m));  // ties -> lower idx wins
            double v = __longlong_as_double((long long)bits);
            // branch-free sorted insert (ascending), static indices only
            #pragma unroll
            for (int i = 0; i < 15; ++i) s[i] = fmin(s[i + 1], fmax(v, s[i]));
            s[15] = fmax(v, s[15]);
        }
    }

    // merge the 4 scanners' lists per query (reuse sD: 4096 doubles <= 4416)
    double* mbuf = sD;
    __syncthreads();
    #pragma unroll
    for (int i = 0; i < 16; ++i) mbuf[(size_t)qq * 64 + sc * 16 + i] = s[i];
    __syncthreads();
    if (tid < 64) {
        double tb[16];
        #pragma unroll
        for (int i = 0; i < 16; ++i) tb[i] = 0.0;
        const double* src = mbuf + (size_t)tid * 64;
        #pragma unroll 4
        for (int e = 0; e < 64; ++e) {
            double v = src[e];
            #pragma unroll
            for (int i = 0; i < 15; ++i) tb[i] = fmin(tb[i + 1], fmax(v, tb[i]));
            tb[15] = fmax(v, tb[15]);
        }
        int* op = idx_out + ((size_t)b * NPTS + q0 + tid) * KNN;
        #pragma unroll
        for (int i = 0; i < 16; ++i) {
            int code = (int)((unsigned long long)__double_as_longlong(tb[i]) & 0xFFFULL);
            op[i] = 4095 - code;
        }
    }
}

// ---------------- K3: P = W1 * x ; Q = (W2 - W1) * x  (both [b][n][o]) --------
__global__ __launch_bounds__(256) void k_pq(const float* __restrict__ x,
                                            const float* __restrict__ W,
                                            float* __restrict__ P,
                                            float* __restrict__ Q) {
    __shared__ __align__(16) float sX[4096];    // [c][m] 64x64
    __shared__ __align__(16) float sWt[8192];   // [c][oc] 64x128 (oc<64:W1, >=64:W2-W1)
    const int tid = threadIdx.x;
    const int g0  = blockIdx.x * 64;            // global row = b*4096 + n
    const int b   = g0 >> 12;
    const int n0  = g0 & 4095;
    const float* xb = x + (size_t)b * NCH * NPTS;

    for (int i = tid; i < 8192; i += 256) {
        int c = i >> 7, oc = i & 127;
        float wv;
        if (oc < 64) wv = W[oc * 128 + c];
        else { int o = oc - 64; wv = W[o * 128 + 64 + c] - W[o * 128 + c]; }
        sWt[c * 128 + oc] = wv;
    }
    for (int i = tid; i < 4096; i += 256) {
        int c = i >> 6, m = i & 63;
        sX[i] = xb[(size_t)c * NPTS + n0 + m];
    }
    __syncthreads();

    const int ty = tid >> 4, tx = tid & 15;     // rows ty*4.., cols tx*4 (P) / 64+tx*4 (Q)
    float aP[4][4], aQ[4][4];
    #pragma unroll
    for (int i = 0; i < 4; ++i)
        #pragma unroll
        for (int j = 0; j < 4; ++j) { aP[i][j] = 0.f; aQ[i][j] = 0.f; }

    const float4* a4 = (const float4*)sX + ty;
    const float4* p4 = (const float4*)sWt + tx;
    const float4* q4 = (const float4*)sWt + 16 + tx;
    #pragma unroll 8
    for (int kk = 0; kk < 64; ++kk) {
        float4 a  = a4[kk * 16];
        float4 wp = p4[kk * 32];
        float4 wq = q4[kk * 32];
        aP[0][0] = fmaf(a.x, wp.x, aP[0][0]); aP[0][1] = fmaf(a.x, wp.y, aP[0][1]);
        aP[0][2] = fmaf(a.x, wp.z, aP[0][2]); aP[0][3] = fmaf(a.x, wp.w, aP[0][3]);
        aP[1][0] = fmaf(a.y, wp.x, aP[1][0]); aP[1][1] = fmaf(a.y, wp.y, aP[1][1]);
        aP[1][2] = fmaf(a.y, wp.z, aP[1][2]); aP[1][3] = fmaf(a.y, wp.w, aP[1][3]);
        aP[2][0] = fmaf(a.z, wp.x, aP[2][0]); aP[2][1] = fmaf(a.z, wp.y, aP[2][1]);
        aP[2][2] = fmaf(a.z, wp.z, aP[2][2]); aP[2][3] = fmaf(a.z, wp.w, aP[2][3]);
        aP[3][0] = fmaf(a.w, wp.x, aP[3][0]); aP[3][1] = fmaf(a.w, wp.y, aP[3][1]);
        aP[3][2] = fmaf(a.w, wp.z, aP[3][2]); aP[3][3] = fmaf(a.w, wp.w, aP[3][3]);
        aQ[0][0] = fmaf(a.x, wq.x, aQ[0][0]); aQ[0][1] = fmaf(a.x, wq.y, aQ[0][1]);
        aQ[0][2] = fmaf(a.x, wq.z, aQ[0][2]); aQ[0][3] = fmaf(a.x, wq.w, aQ[0][3]);
        aQ[1][0] = fmaf(a.y, wq.x, aQ[1][0]); aQ[1][1] = fmaf(a.y, wq.y, aQ[1][1]);
        aQ[1][2] = fmaf(a.y, wq.z, aQ[1][2]); aQ[1][3] = fmaf(a.y, wq.w, aQ[1][3]);
        aQ[2][0] = fmaf(a.z, wq.x, aQ[2][0]); aQ[2][1] = fmaf(a.z, wq.y, aQ[2][1]);
        aQ[2][2] = fmaf(a.z, wq.z, aQ[2][2]); aQ[2][3] = fmaf(a.z, wq.w, aQ[2][3]);
        aQ[3][0] = fmaf(a.w, wq.x, aQ[3][0]); aQ[3][1] = fmaf(a.w, wq.y, aQ[3][1]);
        aQ[3][2] = fmaf(a.w, wq.z, aQ[3][2]); aQ[3][3] = fmaf(a.w, wq.w, aQ[3][3]);
    }
    #pragma unroll
    for (int i = 0; i < 4; ++i) {
        size_t row = (size_t)(g0 + ty * 4 + i) * 64;
        float4 vp; vp.x = aP[i][0]; vp.y = aP[i][1]; vp.z = aP[i][2]; vp.w = aP[i][3];
        float4 vq; vq.x = aQ[i][0]; vq.y = aQ[i][1]; vq.z = aQ[i][2]; vq.w = aQ[i][3];
        ((float4*)(P + row))[tx] = vp;
        ((float4*)(Q + row))[tx] = vq;
    }
}

// ---------------- K4: gather + max/min over k + global sum/sumsq --------------
__global__ __launch_bounds__(256) void k_stats(const float* __restrict__ P,
                                               const float* __restrict__ Q,
                                               const int* __restrict__ idx,
                                               float* __restrict__ Mx,
                                               float* __restrict__ Mn,
                                               float* __restrict__ gsum,
                                               float* __restrict__ gsum2) {
    const int tid = threadIdx.x;
    const int o = tid & 63, ng = tid >> 6;
    const int b = blockIdx.y;
    const int n0 = blockIdx.x * 16;
    const float* Pb = P + (((size_t)b << 12) * 64);
    float ssum = 0.f, ssq = 0.f;
    for (int j = 0; j < 4; ++j) {
        int n = n0 + ng * 4 + j;
        size_t base = ((size_t)b << 12) + n;
        float qv = Q[base * 64 + o];
        const int* ip = idx + base * 16;
        float vmax = -3.4e38f, vmin = 3.4e38f;
        #pragma unroll
        for (int k = 0; k < 16; ++k) {
            int m = ip[k];
            float v = Pb[(size_t)m * 64 + o] + qv;
            vmax = fmaxf(vmax, v);
            vmin = fminf(vmin, v);
            ssum += v;
            ssq  = fmaf(v, v, ssq);
        }
        Mx[base * 64 + o] = vmax;
        Mn[base * 64 + o] = vmin;
    }
    __shared__ float red[8][64];
    red[ng][o] = ssum;
    red[ng + 4][o] = ssq;
    __syncthreads();
    if (tid < 64) {
        float s  = red[0][o] + red[1][o] + red[2][o] + red[3][o];
        float s2 = red[4][o] + red[5][o] + red[6][o] + red[7][o];
        atomicAdd(&gsum[o], s);
        atomicAdd(&gsum2[o], s2);
    }
}

// ---------------- K5: BN + LeakyReLU + transpose to [b][o][n] -----------------
__global__ __launch_bounds__(256) void k_final(const float* __restrict__ Mx,
                                               const float* __restrict__ Mn,
                                               const float* __restrict__ gsum,
                                               const float* __restrict__ gsum2,
                                               const float* __restrict__ gamma,
                                               const float* __restrict__ beta,
                                               float* __restrict__ out) {
    __shared__ float tX[64 * 65], tN[64 * 65];
    const int tid = threadIdx.x;
    const int b = blockIdx.y;
    const int n0 = blockIdx.x * 64;
    size_t base = ((size_t)b << 12) + n0;
    for (int i = tid; i < 4096; i += 256) {
        int nl = i >> 6, o = i & 63;
        tX[nl * 65 + o] = Mx[(base + nl) * 64 + o];
        tN[nl * 65 + o] = Mn[(base + nl) * 64 + o];
    }
    __syncthreads();
    const int lane = tid & 63, wv = tid >> 6;
    const float inv = 1.0f / 524288.0f;
    for (int oo = 0; oo < 16; ++oo) {
        int o = wv * 16 + oo;
        float mean = gsum[o] * inv;
        float var  = gsum2[o] * inv - mean * mean;
        float scv  = gamma[o] * rsqrtf(var + 1e-5f);
        float bsv  = beta[o] - mean * scv;
        float M = (scv >= 0.f) ? tX[lane * 65 + o] : tN[lane * 65 + o];
        float v = fmaf(scv, M, bsv);
        out[((size_t)b * 64 + o) * 4096 + n0 + lane] = (v >= 0.f) ? v : 0.2f * v;
    }
}

extern "C" void kernel_launch(void* const* d_in, const int* in_sizes, int n_in,
                              void* d_out, int out_size, void* d_ws, size_t ws_size,
                              hipStream_t stream) {
    const float* x     = (const float*)d_in[0];
    const float* W     = (const float*)d_in[1];
    const float* gamma = (const float*)d_in[2];
    const float* beta  = (const float*)d_in[3];
    float* out = (float*)d_out;

    char* ws = (char*)d_ws;
    double* xx   = (double*)(ws);                      // 256 KB
    float* gsum  = (float*)(ws + 262144);              // 256 B
    float* gsum2 = (float*)(ws + 262400);              // 256 B
    int*   idx   = (int*)  (ws + 393216);              // 2 MB
    float* P     = (float*)(ws + 2490368);             // 8 MB
    float* Q     = (float*)(ws + 10878976);            // 8 MB
    float* Mx    = (float*)(ws + 19267584);            // 8 MB
    float* Mn    = (float*)(ws + 27656192);            // 8 MB (end ~34.4 MB)

    hipMemsetAsync(gsum, 0, 512, stream);
    k_xx   <<<dim3(128),      256, 0, stream>>>(x, xx);
    k_knn  <<<dim3(64, 8),    256, 0, stream>>>(x, xx, idx);
    k_pq   <<<dim3(512),      256, 0, stream>>>(x, W, P, Q);
    k_stats<<<dim3(256, 8),   256, 0, stream>>>(P, Q, idx, Mx, Mn, gsum, gsum2);
    k_final<<<dim3(64, 8),    256, 0, stream>>>(Mx, Mn, gsum, gsum2, gamma, beta, out);
}